// Round 2
// baseline (283.322 us; speedup 1.0000x reference)
//
#include <hip/hip_runtime.h>

// LocalPredictor: 3x3 conv (32->128, center tap masked) + ReLU + 1x1 conv (128->32)
// B=8, k=32, H=W=256, HIDDEN=128.
// Inputs/outputs are FLOAT32 arrays whose values are bf16-rounded -> convert to
// bf16 in-kernel (lossless truncation) and use bf16 MFMA with fp32 accumulate.

#define NB 8
#define KC 32
#define HH 256
#define WW 256
#define HID 128

typedef __attribute__((ext_vector_type(8))) short short8;
typedef __attribute__((ext_vector_type(4))) float f32x4;

__device__ __forceinline__ unsigned short f2bf(float f) {
    union { float f; unsigned int i; } x; x.f = f;
    unsigned int r = x.i + 0x7FFFu + ((x.i >> 16) & 1u);  // RNE
    return (unsigned short)(r >> 16);
}

// ws layout: w1t bf16[9*HID*KC] (73728 B) | w2t bf16[KC*HID] (8192 B)
// w1t[p][d][c] (c contiguous) so a GEMM1 B-fragment is one 16B load per lane.
__global__ void prep_weights(const float* __restrict__ w1,
                             const float* __restrict__ w2,
                             unsigned short* __restrict__ w1t,
                             unsigned short* __restrict__ w2t) {
    int i = blockIdx.x * 256 + threadIdx.x;
    if (i < 9 * HID * KC) {
        int c = i & 31;            // KC=32
        int d = (i >> 5) & 127;    // HID=128
        int p = i >> 12;
        w1t[i] = f2bf(w1[d * (9 * KC) + c * 9 + p]);
    } else if (i < 9 * HID * KC + KC * HID) {
        int j = i - 9 * HID * KC;
        w2t[j] = f2bf(w2[j]);      // W2 (32,128) row-major kept as-is
    }
}

__global__ __launch_bounds__(256) void local_pred_kernel(
    const float* __restrict__ zg,
    const unsigned short* __restrict__ w1t,
    const float* __restrict__ b1g,
    const unsigned short* __restrict__ w2t,
    const float* __restrict__ b2g,
    float* __restrict__ outg)
{
    // z tile: [dy=3][x=66][c], c-stride 40 elems (80B = 20 banks: uniform 2-way b128
    // reads = free; 16B alignment kept since 80 % 16 == 0).
    __shared__ __attribute__((aligned(16))) unsigned short z_lds[3 * 66 * 40];
    // h: [m=64][d], d-stride 136 elems (272B row: 2-way-free b128 reads, 16B aligned)
    __shared__ __attribute__((aligned(16))) unsigned short h_lds[64 * 136];

    const int tid  = threadIdx.x;
    const int bidx = blockIdx.x;
    const int x0 = (bidx & 3) << 6;        // 4 tiles of 64 along W
    const int y  = (bidx >> 2) & 255;
    const int b  = bidx >> 10;

    // ---------------- stage z halo tile (fp32 -> bf16, zero-pad OOB) ----------------
    for (int i = tid; i < 3 * KC * 66; i += 256) {
        int x  = i % 66;                   // x fastest -> coalesced global reads
        int rc = i / 66;                   // dy*32 + c
        int c  = rc & 31;
        int dy = rc >> 5;
        int gy = y + dy - 1;
        int gx = x0 + x - 1;
        unsigned short v = 0;
        if ((unsigned)gy < (unsigned)HH && (unsigned)gx < (unsigned)WW) {
            union { float f; unsigned int i; } u;
            u.f = zg[(((b * KC + c) * HH) + gy) * WW + gx];
            v = (unsigned short)(u.i >> 16);   // values are exactly bf16: truncate
        }
        z_lds[(dy * 66 + x) * 40 + c] = v;
    }
    __syncthreads();

    const int wave = tid >> 6;
    const int lane = tid & 63;
    const int lr = lane & 15;              // A-row / B-col within 16x16 tile
    const int lq = lane >> 4;              // quad: k = lq*8 + j
    const int wm = wave >> 1;              // 2 M-groups of 32 rows
    const int wn = wave & 1;               // 2 N-groups of 64 cols

    // ---------------- GEMM1: (64 pix) x (128 hid) x (K=8 taps * 32 ch) ----------------
    f32x4 acc[2][4];
#pragma unroll
    for (int mt = 0; mt < 2; ++mt)
#pragma unroll
        for (int nt = 0; nt < 4; ++nt)
            acc[mt][nt] = (f32x4){0.f, 0.f, 0.f, 0.f};

    const int taps[8] = {0, 1, 2, 3, 5, 6, 7, 8};   // center (4) masked out
#pragma unroll
    for (int t = 0; t < 8; ++t) {
        int p  = taps[t];
        int di = p / 3;
        int dj = p % 3;
        short8 afr[2];
#pragma unroll
        for (int mt = 0; mt < 2; ++mt) {
            int m = wm * 32 + mt * 16 + lr;          // pixel x = x0 + m
            afr[mt] = *(const short8*)&z_lds[(di * 66 + (m + dj)) * 40 + lq * 8];
        }
#pragma unroll
        for (int nt = 0; nt < 4; ++nt) {
            int d = wn * 64 + nt * 16 + lr;
            short8 bfr = *(const short8*)&w1t[(p * HID + d) * KC + lq * 8];
#pragma unroll
            for (int mt = 0; mt < 2; ++mt)
                acc[mt][nt] = __builtin_amdgcn_mfma_f32_16x16x32_bf16(
                    afr[mt], bfr, acc[mt][nt], 0, 0, 0);
        }
    }

    // epilogue1: +b1, ReLU, bf16 -> h_lds  (C layout: col=lane&15, row=lq*4+r)
#pragma unroll
    for (int nt = 0; nt < 4; ++nt) {
        int d = wn * 64 + nt * 16 + lr;
        float bias = b1g[d];
#pragma unroll
        for (int mt = 0; mt < 2; ++mt) {
#pragma unroll
            for (int r = 0; r < 4; ++r) {
                float v = acc[mt][nt][r] + bias;
                v = v > 0.f ? v : 0.f;
                int m = wm * 32 + mt * 16 + lq * 4 + r;
                h_lds[m * 136 + d] = f2bf(v);
            }
        }
    }
    __syncthreads();

    // ---------------- GEMM2: (64 pix) x (32 out) x (K=128) ----------------
    f32x4 acc2[2];
    acc2[0] = (f32x4){0.f, 0.f, 0.f, 0.f};
    acc2[1] = (f32x4){0.f, 0.f, 0.f, 0.f};
    const int m2 = wave * 16 + lr;                    // each wave owns 16 pixel rows
#pragma unroll
    for (int k4 = 0; k4 < 4; ++k4) {
        short8 afr = *(const short8*)&h_lds[m2 * 136 + k4 * 32 + lq * 8];
#pragma unroll
        for (int nt = 0; nt < 2; ++nt) {
            short8 bfr = *(const short8*)&w2t[(nt * 16 + lr) * HID + k4 * 32 + lq * 8];
            acc2[nt] = __builtin_amdgcn_mfma_f32_16x16x32_bf16(afr, bfr, acc2[nt], 0, 0, 0);
        }
    }

    // epilogue2: +b2, pack 4 consecutive-x fp32 per lane -> 16B stores
#pragma unroll
    for (int nt = 0; nt < 2; ++nt) {
        int kout = nt * 16 + lr;
        float bias = b2g[kout];
        f32x4 pack;
#pragma unroll
        for (int r = 0; r < 4; ++r)
            pack[r] = acc2[nt][r] + bias;
        int mb = wave * 16 + lq * 4;                  // x = x0 + mb + r, r=0..3
        size_t off = ((size_t)(b * KC + kout) * HH + y) * WW + x0 + mb;
        *(f32x4*)&outg[off] = pack;
    }
}

extern "C" void kernel_launch(void* const* d_in, const int* in_sizes, int n_in,
                              void* d_out, int out_size, void* d_ws, size_t ws_size,
                              hipStream_t stream)
{
    const float* z  = (const float*)d_in[0];
    const float* W1 = (const float*)d_in[1];
    const float* b1 = (const float*)d_in[2];
    const float* W2 = (const float*)d_in[3];
    const float* b2 = (const float*)d_in[4];
    float* out = (float*)d_out;
    unsigned short* w1t = (unsigned short*)d_ws;              // 73728 B
    unsigned short* w2t = (unsigned short*)d_ws + 9 * HID * KC; // +8192 B

    hipLaunchKernelGGL(prep_weights, dim3(160), dim3(256), 0, stream, W1, W2, w1t, w2t);
    hipLaunchKernelGGL(local_pred_kernel, dim3(NB * HH * (WW / 64)), dim3(256), 0, stream,
                       z, w1t, b1, w2t, b2, out);
}

// Round 3
// 188.682 us; speedup vs baseline: 1.5016x; 1.5016x over previous
//
#include <hip/hip_runtime.h>

// LocalPredictor: 3x3 conv (32->128, center masked) + ReLU + 1x1 conv (128->32)
// B=8, k=32, H=W=256, HID=128. fp32 in/out (values bf16-exact) -> bf16 MFMA.
// v3: y-strip blocks (64 wide x 8 tall), 3-row ring buffer, register-batched
// transposing staging (coalesced loads, v_perm pack, b128 LDS writes).

#define KC 32
#define HH 256
#define WW 256
#define HID 128
#define YS 8          // rows per block strip
#define ZROW 2640     // 66 * 40 ushorts per ring row

typedef __attribute__((ext_vector_type(8))) short short8;
typedef __attribute__((ext_vector_type(4))) float f32x4;

__device__ __forceinline__ unsigned short f2bf(float f) {
    union { float f; unsigned int i; } x; x.f = f;
    unsigned int r = x.i + 0x7FFFu + ((x.i >> 16) & 1u);  // RNE
    return (unsigned short)(r >> 16);
}

// ws: w1t bf16[9*HID*KC] | w2t bf16[KC*HID].  w1t[p][d][c], c contiguous.
__global__ void prep_weights(const float* __restrict__ w1,
                             const float* __restrict__ w2,
                             unsigned short* __restrict__ w1t,
                             unsigned short* __restrict__ w2t) {
    int i = blockIdx.x * 256 + threadIdx.x;
    if (i < 9 * HID * KC) {
        int c = i & 31;
        int d = (i >> 5) & 127;
        int p = i >> 12;
        w1t[i] = f2bf(w1[d * (9 * KC) + c * 9 + p]);
    } else if (i < 9 * HID * KC + KC * HID) {
        int j = i - 9 * HID * KC;
        w2t[j] = f2bf(w2[j]);
    }
}

__global__ __launch_bounds__(256) void local_pred_kernel(
    const float* __restrict__ zg,
    const unsigned short* __restrict__ w1t,
    const float* __restrict__ b1g,
    const unsigned short* __restrict__ w2t,
    const float* __restrict__ b2g,
    float* __restrict__ outg)
{
    __shared__ __attribute__((aligned(16))) unsigned short z_lds[3 * ZROW];
    __shared__ __attribute__((aligned(16))) unsigned short h_lds[64 * 136];

    const int tid = threadIdx.x;
    const int l   = tid & 63;      // x-lane for staging
    const int o   = tid >> 6;      // c-octet for staging
    const int bidx = blockIdx.x;
    const int x0 = (bidx & 3) << 6;
    const int y0 = ((bidx >> 2) & 31) * YS;
    const int b  = bidx >> 7;

    const int wave = tid >> 6;
    const int lane = tid & 63;
    const int lr = lane & 15;
    const int lq = lane >> 4;
    const int wm = wave >> 1;
    const int wn = wave & 1;

    const float* zb = zg + (size_t)b * KC * HH * WW;

    // -------- hoisted per-strip constants --------
    float bias1[4];
#pragma unroll
    for (int nt = 0; nt < 4; ++nt) bias1[nt] = b1g[wn * 64 + nt * 16 + lr];
    float bias2[2];
#pragma unroll
    for (int nt = 0; nt < 2; ++nt) bias2[nt] = b2g[nt * 16 + lr];
    short8 w2f[4][2];
#pragma unroll
    for (int k4 = 0; k4 < 4; ++k4)
#pragma unroll
        for (int nt = 0; nt < 2; ++nt)
            w2f[k4][nt] = *(const short8*)&w2t[(nt * 16 + lr) * HID + k4 * 32 + lq * 8];

    const int aoff0 = (wm * 32 + lr) * 40 + lq * 8;
    const int bbase = (wn * 64 + lr) * KC + lq * 8;
    const int m2    = wave * 16 + lr;

    const int ho    = tid >> 1;         // halo c-octet (tid<8)
    const int hside = tid & 1;
    const int hgx   = x0 - 1 + hside * 65;
    const bool hgx_ok = (unsigned)hgx < (unsigned)WW;

    int sA = (y0 + 2) % 3, sB = y0 % 3, sC = (y0 + 1) % 3;   // slots y-1,y,y+1

    // -------- prestage rows y0-1, y0, y0+1 --------
    {
        int slots[3] = {sA, sB, sC};
#pragma unroll
        for (int dy = 0; dy < 3; ++dy) {
            int gy = y0 - 1 + dy;
            int slot = slots[dy];
            bool rowok = (unsigned)gy < (unsigned)HH;
            float m8[8];
            const float* p = zb + ((o * 8) * HH + gy) * WW + x0 + l;
#pragma unroll
            for (int j = 0; j < 8; ++j) m8[j] = rowok ? p[j * HH * WW] : 0.f;
            union { short8 s; unsigned int u[4]; } w;
            union { float f; unsigned int i; } uu[8];
#pragma unroll
            for (int j = 0; j < 8; ++j) uu[j].f = m8[j];
#pragma unroll
            for (int k = 0; k < 4; ++k)
                w.u[k] = __builtin_amdgcn_perm(uu[2 * k + 1].i, uu[2 * k].i, 0x07060302u);
            *(short8*)&z_lds[(slot * 66 + l + 1) * 40 + o * 8] = w.s;
            if (tid < 8) {
                bool ok = rowok && hgx_ok;
                float e8[8];
                const float* q = zb + ((ho * 8) * HH + gy) * WW + hgx;
#pragma unroll
                for (int j = 0; j < 8; ++j) e8[j] = ok ? q[j * HH * WW] : 0.f;
                union { short8 s; unsigned int u[4]; } we;
                union { float f; unsigned int i; } ue[8];
#pragma unroll
                for (int j = 0; j < 8; ++j) ue[j].f = e8[j];
#pragma unroll
                for (int k = 0; k < 4; ++k)
                    we.u[k] = __builtin_amdgcn_perm(ue[2 * k + 1].i, ue[2 * k].i, 0x07060302u);
                *(short8*)&z_lds[(slot * 66 + hside * 65) * 40 + ho * 8] = we.s;
            }
        }
    }

    const int tap_di[8] = {0, 0, 0, 1, 1, 2, 2, 2};
    const int tap_dj[8] = {0, 1, 2, 0, 2, 0, 1, 2};

    for (int r = 0; r < YS; ++r) {
        const int y = y0 + r;
        __syncthreads();   // A: z(y+1) staged, h free

        // ---------------- GEMM1: M=64, N=128, K=256 ----------------
        f32x4 acc[2][4];
#pragma unroll
        for (int mt = 0; mt < 2; ++mt)
#pragma unroll
            for (int nt = 0; nt < 4; ++nt)
                acc[mt][nt] = (f32x4){0.f, 0.f, 0.f, 0.f};

        const int rowoff[3] = {sA * ZROW, sB * ZROW, sC * ZROW};
#pragma unroll
        for (int t = 0; t < 8; ++t) {
            const int di = tap_di[t], dj = tap_dj[t];
            const int abase = rowoff[di] + dj * 40 + aoff0;
            short8 afr[2];
            afr[0] = *(const short8*)&z_lds[abase];
            afr[1] = *(const short8*)&z_lds[abase + 16 * 40];
            const int p = di * 3 + dj;
#pragma unroll
            for (int nt = 0; nt < 4; ++nt) {
                short8 bfr = *(const short8*)&w1t[p * (HID * KC) + nt * 512 + bbase];
#pragma unroll
                for (int mt = 0; mt < 2; ++mt)
                    acc[mt][nt] = __builtin_amdgcn_mfma_f32_16x16x32_bf16(
                        afr[mt], bfr, acc[mt][nt], 0, 0, 0);
            }
        }

        // epilogue1: +b1, ReLU, bf16 -> h_lds
#pragma unroll
        for (int nt = 0; nt < 4; ++nt) {
            int d = wn * 64 + nt * 16 + lr;
#pragma unroll
            for (int mt = 0; mt < 2; ++mt) {
#pragma unroll
                for (int rr = 0; rr < 4; ++rr) {
                    float v = acc[mt][nt][rr] + bias1[nt];
                    v = v > 0.f ? v : 0.f;
                    int m = wm * 32 + mt * 16 + lq * 4 + rr;
                    h_lds[m * 136 + d] = f2bf(v);
                }
            }
        }
        __syncthreads();   // B: h ready; slot sA free

        // ---- issue stage loads for row y+2 ----
        const bool dostage = (r < YS - 1);
        const int gy = y + 2;
        const bool rowok = dostage && ((unsigned)gy < (unsigned)HH);
        float m8[8], e8[8];
        {
            const float* p = zb + ((o * 8) * HH + gy) * WW + x0 + l;
#pragma unroll
            for (int j = 0; j < 8; ++j) m8[j] = rowok ? p[j * HH * WW] : 0.f;
            bool ok = rowok && hgx_ok && (tid < 8);
            const float* q = zb + ((ho * 8) * HH + gy) * WW + hgx;
#pragma unroll
            for (int j = 0; j < 8; ++j) e8[j] = ok ? q[j * HH * WW] : 0.f;
        }

        // ---------------- GEMM2: M=64, N=32, K=128 ----------------
        f32x4 acc2[2];
        acc2[0] = (f32x4){0.f, 0.f, 0.f, 0.f};
        acc2[1] = (f32x4){0.f, 0.f, 0.f, 0.f};
#pragma unroll
        for (int k4 = 0; k4 < 4; ++k4) {
            short8 afr = *(const short8*)&h_lds[m2 * 136 + k4 * 32 + lq * 8];
#pragma unroll
            for (int nt = 0; nt < 2; ++nt)
                acc2[nt] = __builtin_amdgcn_mfma_f32_16x16x32_bf16(afr, w2f[k4][nt],
                                                                   acc2[nt], 0, 0, 0);
        }

        // epilogue2: +b2, 16B coalesced stores
#pragma unroll
        for (int nt = 0; nt < 2; ++nt) {
            int kout = nt * 16 + lr;
            f32x4 pack;
#pragma unroll
            for (int rr = 0; rr < 4; ++rr) pack[rr] = acc2[nt][rr] + bias2[nt];
            int mb = wave * 16 + lq * 4;
            size_t off = ((size_t)(b * KC + kout) * HH + y) * WW + x0 + mb;
            *(f32x4*)&outg[off] = pack;
        }

        // ---- commit stage into slot sA ----
        if (dostage) {
            union { short8 s; unsigned int u[4]; } w;
            union { float f; unsigned int i; } uu[8];
#pragma unroll
            for (int j = 0; j < 8; ++j) uu[j].f = m8[j];
#pragma unroll
            for (int k = 0; k < 4; ++k)
                w.u[k] = __builtin_amdgcn_perm(uu[2 * k + 1].i, uu[2 * k].i, 0x07060302u);
            *(short8*)&z_lds[(sA * 66 + l + 1) * 40 + o * 8] = w.s;
            if (tid < 8) {
                union { short8 s; unsigned int u[4]; } we;
                union { float f; unsigned int i; } ue[8];
#pragma unroll
                for (int j = 0; j < 8; ++j) ue[j].f = e8[j];
#pragma unroll
                for (int k = 0; k < 4; ++k)
                    we.u[k] = __builtin_amdgcn_perm(ue[2 * k + 1].i, ue[2 * k].i, 0x07060302u);
                *(short8*)&z_lds[(sA * 66 + hside * 65) * 40 + ho * 8] = we.s;
            }
        }
        int t0 = sA; sA = sB; sB = sC; sC = t0;   // rotate ring
    }
}

extern "C" void kernel_launch(void* const* d_in, const int* in_sizes, int n_in,
                              void* d_out, int out_size, void* d_ws, size_t ws_size,
                              hipStream_t stream)
{
    const float* z  = (const float*)d_in[0];
    const float* W1 = (const float*)d_in[1];
    const float* b1 = (const float*)d_in[2];
    const float* W2 = (const float*)d_in[3];
    const float* b2 = (const float*)d_in[4];
    float* out = (float*)d_out;
    unsigned short* w1t = (unsigned short*)d_ws;                // 73728 B
    unsigned short* w2t = (unsigned short*)d_ws + 9 * HID * KC; // + 8192 B

    hipLaunchKernelGGL(prep_weights, dim3(160), dim3(256), 0, stream, W1, W2, w1t, w2t);
    hipLaunchKernelGGL(local_pred_kernel, dim3(8 * 4 * (HH / YS)), dim3(256), 0, stream,
                       z, w1t, b1, w2t, b2, out);
}